// Round 10
// baseline (374.169 us; speedup 1.0000x reference)
//
#include <hip/hip_runtime.h>
#include <hip/hip_bf16.h>
#include <math.h>

// ArcFace loss, MI355X. B=2048, D=512, C=32768.
// R16b: barrier-free GEMM (R16 resubmit after infra failure, plus a
// bank-conflict fix found in review). Evidence: MfmaUtil pinned at 13-17%
// across three occupancies (R13 21%, R14 39%, R15b 56%) with MFMA-busy ==
// 13-15us pipe floor each time -> the lockstep ping-pong/barrier structure
// is the wall, not any single pipe. Restructure:
//   - Block = 64 N-rows (B tile = 32 KB LDS) x M-half (1024 rows).
//     B staged ONCE per block (8 global_load_lds/thread), ONE barrier,
//     then the main loop has NO barriers: waves run free.
//   - B LDS swizzle (fix): with 512B row stride, row*512 contributes 0 to
//     the bank index, so stored position p = j ^ (row&7) (j = global 16B
//     unit 0..31): fixed fragment unit -> 8 consecutive rows hit 8
//     distinct bank-quads (<=2 lanes/bank per phase = free, m136).
//     Read: off = row*512 + ((unit)^(row&3))*16 + (s*64 ^ ((row&4)<<4)).
//   - Wave (4/block) owns 4 chunks of 64 M-rows; per chunk per K-slab:
//     4 coalesced A-loads + 4 ds_reads + 4 MFMAs (acc 2x2 = 64 AGPR),
//     A 2-deep register prefetch (apre[parity], static idx).
//   - prep writes A in a NEW layout (fbp) so GEMM A-fragment loads are
//     fully coalesced (addr = base(c32,s,p) + lane*16); byte-identical
//     operand bytes to R15b's verified a-frag.
//   - Per-chunk epilogue: exp + DPP row-reduce, lanes 31/63 atomicAdd
//     straight to global rowsum (each m touched once per block; no lsum).
//   - (256,3): 3 blocks/CU resident (LDS 32KB; cap 170: arch ~80 + 64
//     AGPR fits -> no spill by the R11-R13 split rule).
//   - Grid 1024 = {ngroup 64}x{mhalf 2}x{xcd 8}, ntile = ngroup*8+xcd
//     (XCD-bijective); per-XCD B slice 2MB -> L2-resident.
// MX-scaled fp8 MFMA (32x32x64, unit scales 0x7F) bit-exact since R11.
// Weights path (wb8), tgt, loss unchanged.

#define BN 2048
#define DK 512
#define CN 32768

typedef __attribute__((ext_vector_type(4))) float floatx4;
typedef __attribute__((ext_vector_type(16))) float floatx16;
typedef __attribute__((ext_vector_type(2))) long longx2;
typedef __attribute__((ext_vector_type(4))) long longx4;
typedef __attribute__((ext_vector_type(8))) int intx8;

__device__ inline float dot4(floatx4 a, floatx4 b) {
  return a.x * b.x + a.y * b.y + a.z * b.z + a.w * b.w;
}

__device__ inline int pack_fp8x4(floatx4 v) {
  int r = __builtin_amdgcn_cvt_pk_fp8_f32(v.x, v.y, 0, false);
  r = __builtin_amdgcn_cvt_pk_fp8_f32(v.z, v.w, r, true);
  return r;
}

// dword j (0..15) of a 64B slab -> MFMA-ready position:
// q=(j>>1)&3 (8B piece), p=j>>3 (k-step), dest = q*4 + p*2 + (j&1)
__device__ inline int permute16(int j) {
  return ((j >> 1) & 3) * 4 + (j >> 3) * 2 + (j & 1);
}

// fbp (A') dword index for within-row dword position D of feature row
// i = c32*32 + r31: s=D>>4 (64B slab), w=D&15, h=w>>3 (k-half),
// p=(w>>2)&1 (16B piece), q=w&3.
__device__ inline int fbp_idx(int c32, int D, int r31) {
  const int s = D >> 4;
  const int w = D & 15;
  return ((c32 * 8 + s) * 2 + ((w >> 2) & 1)) * 256 + (w >> 3) * 128 +
         r31 * 4 + (w & 3);
}

__device__ inline void async_ld16(const void* g, void* l) {
  __builtin_amdgcn_global_load_lds(
      (const __attribute__((address_space(1))) void*)g,
      (__attribute__((address_space(3))) void*)l, 16, 0, 0);
}

// DPP-based add: v += dpp(v, CTRL); invalid lanes contribute 0 (bound_ctrl).
// 0x111/2/4/8 = row_shr:1/2/4/8, 0x142 = row_bcast15.
template <int CTRL>
__device__ inline float dpp_add(float v) {
  int t = __builtin_amdgcn_update_dpp(0, __float_as_int(v), CTRL, 0xf, 0xf,
                                      true);
  return v + __int_as_float(t);
}

// ---- kernel 1: fused prep -> fp8 rows (512 B each).
// Weights -> wb8 (MFMA-ready per-row order, unchanged).
// Features -> fbp (coalesced-fragment A' layout, see header).
__global__ void prep_kernel(const float* __restrict__ feat,
                            const int* __restrict__ y,
                            const float* __restrict__ w,
                            int* __restrict__ fbp,     // A' 1 MB
                            int* __restrict__ wb8,     // [CN][128] dwords
                            float* __restrict__ tgt,
                            float* __restrict__ rowsum) {
  const int wave = threadIdx.x >> 6;
  const int l = threadIdx.x & 63;
  const int D0 = ((l >> 4) * 16)       + permute16(l & 15);
  const int D1 = ((4 + (l >> 4)) * 16) + permute16(l & 15);
  if (blockIdx.x < 8192) {
    const int row = blockIdx.x * 4 + wave;
    const floatx4* src = (const floatx4*)(w + (size_t)row * DK);
    floatx4 v0 = src[l];
    floatx4 v1 = src[64 + l];
    float s = dot4(v0, v0) + dot4(v1, v1);
#pragma unroll
    for (int off = 1; off < 64; off <<= 1) s += __shfl_xor(s, off, 64);
    const float scale = 1.0f / fmaxf(sqrtf(s), 1e-12f);
    v0 *= scale; v1 *= scale;
    int* db = wb8 + (size_t)row * 128;
    db[D0] = pack_fp8x4(v0);
    db[D1] = pack_fp8x4(v1);
  } else {
    const int i = (blockIdx.x - 8192) * 4 + wave;
    const floatx4* src = (const floatx4*)(feat + (size_t)i * DK);
    floatx4 v0 = src[l];
    floatx4 v1 = src[64 + l];
    const int cls = y[i];
    const floatx4* wr = (const floatx4*)(w + (size_t)cls * DK);
    floatx4 w0 = wr[l], w1 = wr[64 + l];
    float s  = dot4(v0, v0) + dot4(v1, v1);
    float d  = dot4(v0, w0) + dot4(v1, w1);
    float wn = dot4(w0, w0) + dot4(w1, w1);
#pragma unroll
    for (int off = 1; off < 64; off <<= 1) {
      s  += __shfl_xor(s, off, 64);
      d  += __shfl_xor(d, off, 64);
      wn += __shfl_xor(wn, off, 64);
    }
    const float fscale = 1.0f / fmaxf(sqrtf(s), 1e-12f);
    v0 *= fscale; v1 *= fscale;
    const int c32 = i >> 5, r31 = i & 31;
    fbp[fbp_idx(c32, D0, r31)] = pack_fp8x4(v0);
    fbp[fbp_idx(c32, D1, r31)] = pack_fp8x4(v1);
    if (l == 0) {
      tgt[i] = d * fscale / fmaxf(sqrtf(wn), 1e-12f);
      rowsum[i] = 0.0f;
    }
  }
}

// ---- kernel 2: B-resident barrier-free MX-fp8 GEMM (32x32x64, unit
// scales) + fused exp row-sum. 256 threads (4 waves), block = 64 N x
// 1024 M-half; wave = 64x64 chunks x 4.
__launch_bounds__(256, 3)
__global__ void gemm_exp_kernel(const char* __restrict__ fbp,   // A' 1 MB
                                const char* __restrict__ wb8,   // [CN][512] B
                                float* __restrict__ rowsum) {
  __shared__ char Bs[64 * 512];   // 32 KB, resident whole kernel

  const int tid  = threadIdx.x;
  const int wave = tid >> 6;
  const int lane = tid & 63;

  const int bid    = blockIdx.x;
  const int xcd    = bid & 7;
  const int mhalf  = (bid >> 3) & 1;
  const int ngroup = bid >> 4;                 // 0..63
  const int ntile  = ngroup * 8 + xcd;         // 0..511, XCD-bijective
  const size_t tileN = (size_t)ntile * 64;
  const int mbase  = mhalf * 1024;

  // ---- stage B tile once: 64 rows x 512 B. Chunk c = i*256+tid ->
  // row r = c>>5, stored pos p = c&31 holds global 16B-unit j = p^(r&7)
  // (bank-spreading swizzle; bijective per row). LDS dest linear in c
  // (= wave-uniform base + lane*16).
#pragma unroll
  for (int i = 0; i < 8; ++i) {
    const int c = i * 256 + tid;
    const int r = c >> 5;
    const int j = (c & 31) ^ (r & 7);
    async_ld16(wb8 + (tileN + r) * 512 + j * 16,
               &Bs[i * 4096 + wave * 1024]);
  }
  __syncthreads();   // the ONLY barrier: B resident for all waves

  const int r31 = lane & 31;
  const int q2  = (lane >> 5) * 2;
  const int qrow = (lane >> 5) * 4;

  // B fragment LDS offsets. Global unit j0 = s*4+q (q=q2 or q2+1) of row
  // is stored at p = j0 ^ (row&7); byte = row*512 + p*16 decomposes as
  // row*512 + (q^(row&3))*16  +  (s*64 ^ ((row&4)<<4)).
  int offBlo[2], offBhi[2], sfl[2];
#pragma unroll
  for (int tj = 0; tj < 2; ++tj) {
    const int row = tj * 32 + r31;
    offBlo[tj] = row * 512 + ((q2    ) ^ (row & 3)) * 16;
    offBhi[tj] = row * 512 + ((q2 + 1) ^ (row & 3)) * 16;
    sfl[tj]    = (row & 4) << 4;    // 0 or 64
  }

  // ---- main loop: 4 chunks of 64 M-rows per wave, no barriers.
  for (int cc = 0; cc < 4; ++cc) {
    const int chunk64 = cc * 4 + wave;          // 0..15 within M-half
    // A' bases for (ti, piece): byte = c32*16384 + s*2048 + p*1024 + lane*16
    const char* gA00 = fbp + (size_t)(mhalf * 32 + chunk64 * 2) * 16384
                       + lane * 16;
    const char* gA01 = gA00 + 1024;
    const char* gA10 = gA00 + 16384;
    const char* gA11 = gA00 + 16384 + 1024;

    longx2 apre[2][2][2];   // [parity][ti][piece], statically indexed
    apre[0][0][0] = *(const longx2*)(gA00);
    apre[0][0][1] = *(const longx2*)(gA01);
    apre[0][1][0] = *(const longx2*)(gA10);
    apre[0][1][1] = *(const longx2*)(gA11);

    floatx16 acc[2][2];
#pragma unroll
    for (int ti = 0; ti < 2; ++ti)
#pragma unroll
      for (int tj = 0; tj < 2; ++tj)
#pragma unroll
        for (int r = 0; r < 16; ++r)
          acc[ti][tj][r] = 0.0f;

#pragma unroll
    for (int s = 0; s < 8; ++s) {
      const int cur = s & 1;
      if (s < 7) {
        const int nxt = cur ^ 1;
        apre[nxt][0][0] = *(const longx2*)(gA00 + (s + 1) * 2048);
        apre[nxt][0][1] = *(const longx2*)(gA01 + (s + 1) * 2048);
        apre[nxt][1][0] = *(const longx2*)(gA10 + (s + 1) * 2048);
        apre[nxt][1][1] = *(const longx2*)(gA11 + (s + 1) * 2048);
      }
      const int so0 = (s * 64) ^ sfl[0];
      const int so1 = (s * 64) ^ sfl[1];
      longx2 blo0 = *(const longx2*)(Bs + offBlo[0] + so0);
      longx2 bhi0 = *(const longx2*)(Bs + offBhi[0] + so0);
      longx2 blo1 = *(const longx2*)(Bs + offBlo[1] + so1);
      longx2 bhi1 = *(const longx2*)(Bs + offBhi[1] + so1);
      intx8 a0 = (intx8)(longx4){apre[cur][0][0].x, apre[cur][0][0].y,
                                 apre[cur][0][1].x, apre[cur][0][1].y};
      intx8 a1 = (intx8)(longx4){apre[cur][1][0].x, apre[cur][1][0].y,
                                 apre[cur][1][1].x, apre[cur][1][1].y};
      intx8 b0 = (intx8)(longx4){blo0.x, blo0.y, bhi0.x, bhi0.y};
      intx8 b1 = (intx8)(longx4){blo1.x, blo1.y, bhi1.x, bhi1.y};
      // 4 MX-scaled MFMAs, K=64, unit scales (0x7F = 2^0): per-product
      // identical to non-scaled fp8; A and B share the same k-permutation
      // so the contraction is exact (bit-exact since R11).
      acc[0][0] = __builtin_amdgcn_mfma_scale_f32_32x32x64_f8f6f4(
          a0, b0, acc[0][0], 0, 0, 0, 0x7f7f7f7f, 0, 0x7f7f7f7f);
      acc[0][1] = __builtin_amdgcn_mfma_scale_f32_32x32x64_f8f6f4(
          a0, b1, acc[0][1], 0, 0, 0, 0x7f7f7f7f, 0, 0x7f7f7f7f);
      acc[1][0] = __builtin_amdgcn_mfma_scale_f32_32x32x64_f8f6f4(
          a1, b0, acc[1][0], 0, 0, 0, 0x7f7f7f7f, 0, 0x7f7f7f7f);
      acc[1][1] = __builtin_amdgcn_mfma_scale_f32_32x32x64_f8f6f4(
          a1, b1, acc[1][1], 0, 0, 0, 0x7f7f7f7f, 0, 0x7f7f7f7f);
    }

    // chunk epilogue: rowsum[m] += sum over this block's 64 N-cols of
    // exp(64*wf). C/D 32x32: col=lane&31, row=(r&3)+8*(r>>2)+4*(lane>>5).
    // DPP row_shr 1/2/4/8 + row_bcast15 -> lanes 31/63 hold the 32-col
    // sums; each m touched once per block -> direct global atomic.
    const int mrow0 = mbase + chunk64 * 64;
#pragma unroll
    for (int ti = 0; ti < 2; ++ti) {
#pragma unroll
      for (int r = 0; r < 16; ++r) {
        float v = __expf(64.0f * acc[ti][0][r]) +
                  __expf(64.0f * acc[ti][1][r]);
        v = dpp_add<0x111>(v);
        v = dpp_add<0x112>(v);
        v = dpp_add<0x114>(v);
        v = dpp_add<0x118>(v);
        v = dpp_add<0x142>(v);
        if ((lane & 31) == 31)
          atomicAdd(&rowsum[mrow0 + ti * 32 + qrow + (r & 3) + 8 * (r >> 2)],
                    v);
      }
    }
  }
}

// ---- kernel 3: final loss
__global__ void loss_kernel(const float* __restrict__ tgt,
                            const float* __restrict__ rowsum,
                            float* __restrict__ out) {
  __shared__ float wsum[8];
  const int t = threadIdx.x;
  float sum = 0.f;
  const float cM = 0.87758256189037271f;  // cos(0.5)
  const float sM = 0.47942553860420301f;  // sin(0.5)
  for (int i = t; i < BN; i += 512) {
    const float tg_raw = tgt[i];
    const float tg = fminf(fmaxf(tg_raw, -1.f + 1e-7f), 1.f - 1e-7f);
    const float num = 64.f * (tg * cM - sqrtf(fmaxf(1.f - tg * tg, 0.f)) * sM);
    const float den = expf(num) + rowsum[i] - expf(64.f * tg_raw);
    sum += num - logf(den);
  }
#pragma unroll
  for (int off = 1; off < 64; off <<= 1) sum += __shfl_xor(sum, off, 64);
  if ((t & 63) == 0) wsum[t >> 6] = sum;
  __syncthreads();
  if (t == 0) {
    float tot = 0.f;
#pragma unroll
    for (int k = 0; k < 8; ++k) tot += wsum[k];
    out[0] = -tot * (1.0f / (float)BN);
  }
}

extern "C" void kernel_launch(void* const* d_in, const int* in_sizes, int n_in,
                              void* d_out, int out_size, void* d_ws, size_t ws_size,
                              hipStream_t stream) {
  const float* features = (const float*)d_in[0];
  const int*   y_true   = (const int*)d_in[1];
  const float* weight   = (const float*)d_in[2];
  float* out = (float*)d_out;

  char* ws = (char*)d_ws;
  char* wb8    = ws;                          // 16 MB
  char* fbp    = ws + 16777216;               //  1 MB (A' layout)
  float* tgt    = (float*)(ws + 17825792);    //  8 KB
  float* rowsum = (float*)(ws + 17833984);    //  8 KB

  prep_kernel<<<8192 + 512, 256, 0, stream>>>(features, y_true, weight,
                                              (int*)fbp, (int*)wb8, tgt, rowsum);
  gemm_exp_kernel<<<1024, 256, 0, stream>>>(fbp, wb8, rowsum);
  loss_kernel<<<1, 512, 0, stream>>>(tgt, rowsum, out);
}